// Round 12
// baseline (214.419 us; speedup 1.0000x reference)
//
#include <hip/hip_runtime.h>
#include <hip/hip_bf16.h>

// MultiDilatelocalAttention, round 12:
// - attention rebuilt as LDS-tiled: block = (branch, image, 8x8 token tile);
//   K/V halo staged once into LDS (zero-filled OOB), taps read via
//   ds_read_b128 from a 560B-stride layout (conflict-free). Fixes the
//   VMEM-issue-bound regime (76 -> ~29 loads/thread).
// - QKV + proj GEMMs: round-8 exact (2-buf, counted vmcnt, XCD remap).
// - conv_all unchanged. qkv stride back to 1152 (no padding).

#define NTOK 50176
#define ROWQKV 1152
#define CDIM 384

typedef _Float16 half2v __attribute__((ext_vector_type(2)));
typedef _Float16 half8 __attribute__((ext_vector_type(8)));
typedef float floatx4 __attribute__((ext_vector_type(4)));

typedef __attribute__((address_space(1))) const unsigned int GU32;
typedef __attribute__((address_space(3))) unsigned int LU32;

// ---------------- fused fp32 -> fp16 conversion: x, w_qkv, w_proj ----------------
#define N_X4 (NTOK * CDIM / 4)
#define N_Q4 (ROWQKV * CDIM / 4)
#define N_P4 (CDIM * CDIM / 4)

__global__ __launch_bounds__(256) void conv_all(const float* __restrict__ x,
                                                const float* __restrict__ wq,
                                                const float* __restrict__ wp,
                                                _Float16* __restrict__ xh,
                                                _Float16* __restrict__ wqh,
                                                _Float16* __restrict__ wph) {
  const int total = N_X4 + N_Q4 + N_P4;
  int i = blockIdx.x * 256 + threadIdx.x;
  const int stride = gridDim.x * 256;
  for (; i < total; i += stride) {
    const float* src;
    _Float16* dst;
    int k;
    if (i < N_X4) { src = x; dst = xh; k = i; }
    else if (i < N_X4 + N_Q4) { src = wq; dst = wqh; k = i - N_X4; }
    else { src = wp; dst = wph; k = i - N_X4 - N_Q4; }
    float4 v = ((const float4*)src)[k];
    union { _Float16 h[4]; uint2 u; } o;
    o.h[0] = (_Float16)v.x; o.h[1] = (_Float16)v.y;
    o.h[2] = (_Float16)v.z; o.h[3] = (_Float16)v.w;
    ((uint2*)dst)[k] = o.u;
  }
}

// ---------------- f16 MFMA GEMM (round-8 exact): C = A * B^T, dbuf + vmcnt(4) ----------------
template <bool HALF_OUT>
__global__ __launch_bounds__(256) void gemm3(const _Float16* __restrict__ A,
                                             const _Float16* __restrict__ B,
                                             const float* __restrict__ bias,
                                             void* __restrict__ Cout,
                                             int N, int K) {
  __shared__ _Float16 Asl[2][128 * 32];
  __shared__ _Float16 Bsl[2][128 * 32];
  const int tid = threadIdx.x;
  const int lane = tid & 63;
  const int wv = tid >> 6;
  const int wr = wv >> 1, wc = wv & 1;

  const int nN = N >> 7;
  const int p = blockIdx.x;
  const int l = (p & 7) * (gridDim.x >> 3) + (p >> 3);
  const size_t row0 = (size_t)(l / nN) * 128;
  const int col0 = (l % nN) * 128;
  const int NT = K / 32;

  const int srow = tid >> 2;
  const int gslot = (tid & 3) ^ ((srow >> 1) & 3);
  const _Float16* Abase = A + (row0 + srow) * (size_t)K + gslot * 8;
  const _Float16* Bbase = B + ((size_t)(col0 + srow)) * (size_t)K + gslot * 8;
  char* AsB = (char*)Asl;
  char* BsB = (char*)Bsl;

  auto stage = [&](int k0, int buf) {
    __builtin_amdgcn_global_load_lds((GU32*)(Abase + k0),
                                     (LU32*)(AsB + buf * 8192 + tid * 16), 16, 0, 0);
    __builtin_amdgcn_global_load_lds((GU32*)(Abase + (size_t)64 * K + k0),
                                     (LU32*)(AsB + buf * 8192 + tid * 16 + 4096), 16, 0, 0);
    __builtin_amdgcn_global_load_lds((GU32*)(Bbase + k0),
                                     (LU32*)(BsB + buf * 8192 + tid * 16), 16, 0, 0);
    __builtin_amdgcn_global_load_lds((GU32*)(Bbase + (size_t)64 * K + k0),
                                     (LU32*)(BsB + buf * 8192 + tid * 16 + 4096), 16, 0, 0);
  };

  const int fr = lane & 15;
  const int fq = lane >> 4;
  const int rpos = (fq ^ ((fr >> 1) & 3)) * 8;

  floatx4 acc[4][4];
#pragma unroll
  for (int i = 0; i < 4; ++i)
#pragma unroll
    for (int j = 0; j < 4; ++j) acc[i][j] = (floatx4){0.f, 0.f, 0.f, 0.f};

  stage(0, 0);
  asm volatile("s_waitcnt vmcnt(0)" ::: "memory");
  __builtin_amdgcn_s_barrier();

  int cur = 0;
  for (int t = 0; t < NT; ++t) {
    if (t + 1 < NT) {
      stage((t + 1) * 32, cur ^ 1);
      asm volatile("s_waitcnt vmcnt(4)" ::: "memory");
    } else {
      asm volatile("s_waitcnt vmcnt(0)" ::: "memory");
    }
    __builtin_amdgcn_s_barrier();
    __builtin_amdgcn_sched_barrier(0);
    half8 af[4], bf[4];
#pragma unroll
    for (int f = 0; f < 4; ++f) {
      af[f] = *(const half8*)&Asl[cur][(wr * 64 + f * 16 + fr) * 32 + rpos];
      bf[f] = *(const half8*)&Bsl[cur][(wc * 64 + f * 16 + fr) * 32 + rpos];
    }
#pragma unroll
    for (int i = 0; i < 4; ++i)
#pragma unroll
      for (int j = 0; j < 4; ++j)
        acc[i][j] = __builtin_amdgcn_mfma_f32_16x16x32_f16(af[i], bf[j], acc[i][j], 0, 0, 0);
    __builtin_amdgcn_sched_barrier(0);
    __builtin_amdgcn_s_barrier();
    cur ^= 1;
  }

  const int crow = wr * 64 + (lane >> 4) * 4;
  const int ccol = wc * 64 + (lane & 15);
#pragma unroll
  for (int fm = 0; fm < 4; ++fm) {
#pragma unroll
    for (int fn = 0; fn < 4; ++fn) {
      const size_t r0 = (row0 + crow + fm * 16) * (size_t)N + col0 + ccol + fn * 16;
      if (HALF_OUT) {
        _Float16* Cc = (_Float16*)Cout;
#pragma unroll
        for (int j = 0; j < 4; ++j) Cc[r0 + (size_t)j * N] = (_Float16)acc[fm][fn][j];
      } else {
        float* Cc = (float*)Cout;
        const float bz = bias[col0 + ccol + fn * 16];
#pragma unroll
        for (int j = 0; j < 4; ++j) Cc[r0 + (size_t)j * N] = acc[fm][fn][j] + bz;
      }
    }
  }
}

// ---------------- LDS-tiled local attention ----------------
// Block = (8x8 token tile, image, branch). Threads: tok = tid>>2 (raster ly,lx),
// head = tid&3. K/V halo (H=8+2*DIL squared rows) staged to LDS once, zero-filled
// OOB; row stride 560B (k[0,256) | v[256,512) | pad) -> conflict-free b128 reads.
template <int DIL>
__global__ __launch_bounds__(256) void attn_tile(const _Float16* __restrict__ qkv,
                                                 _Float16* __restrict__ y) {
  constexpr int H = 8 + 2 * DIL;
  constexpr int NROW = H * H;
  __shared__ char kv[NROW * 560];
  const int tid = threadIdx.x;
  const int head = tid & 3;
  const int tok = tid >> 2;        // 0..63
  const int ly = tok >> 3, lx = tok & 7;
  const int branch = DIL - 1;
  const int cb = branch * 128;
  const int bimg = blockIdx.y;
  const int ty0 = (blockIdx.x / 7) * 8;
  const int tx0 = (blockIdx.x % 7) * 8;
  const size_t base = (size_t)bimg * 3136;
  const float scale = 0.17677669529663687f;  // 1/sqrt(32)

  // ---- stage K/V halo (each row: 16 k-granules + 16 v-granules of 16B) ----
  constexpr int NG = NROW * 32;
  for (int g = tid; g < NG; g += 256) {
    const int r = g >> 5, sl = g & 31;
    const int gy = ty0 - DIL + r / H;
    const int gx = tx0 - DIL + r % H;
    uint4 val = make_uint4(0u, 0u, 0u, 0u);
    if ((unsigned)gy < 56u && (unsigned)gx < 56u) {
      const int off = (sl < 16) ? (384 + cb + sl * 8) : (768 + cb + (sl - 16) * 8);
      val = *(const uint4*)(qkv + (base + gy * 56 + gx) * ROWQKV + off);
    }
    *(uint4*)(kv + r * 560 + sl * 16) = val;
  }

  // q for this (token, head) — global load overlaps staging
  const int gty = ty0 + ly, gtx = tx0 + lx;
  const _Float16* qp = qkv + (base + gty * 56 + gtx) * ROWQKV + cb + head * 32;
  half2v qh[16];
  *(half8*)&qh[0] = *(const half8*)(qp);
  *(half8*)&qh[4] = *(const half8*)(qp + 8);
  *(half8*)&qh[8] = *(const half8*)(qp + 16);
  *(half8*)&qh[12] = *(const half8*)(qp + 24);

  __syncthreads();

  // tap -> halo row index (local): (ly + DIL + dy*DIL)*H + (lx + DIL + dx*DIL)
  int rtap[9];
#pragma unroll
  for (int j = 0; j < 9; ++j) {
    const int dy = j / 3 - 1, dx = j % 3 - 1;
    rtap[j] = (ly + DIL + dy * DIL) * H + (lx + DIL + dx * DIL);
  }

  // pass 1: logits (k from LDS; OOB rows are zero -> logit 0, matching zero-pad)
  float l[9];
#pragma unroll
  for (int j = 0; j < 9; ++j) {
    const char* kp = kv + rtap[j] * 560 + head * 64;
    half2v kh[16];
    *(half8*)&kh[0] = *(const half8*)(kp);
    *(half8*)&kh[4] = *(const half8*)(kp + 16);
    *(half8*)&kh[8] = *(const half8*)(kp + 32);
    *(half8*)&kh[12] = *(const half8*)(kp + 48);
    float d = 0.f;
#if __has_builtin(__builtin_amdgcn_fdot2)
#pragma unroll
    for (int c = 0; c < 16; ++c) d = __builtin_amdgcn_fdot2(qh[c], kh[c], d, false);
#else
#pragma unroll
    for (int c = 0; c < 16; ++c)
      d += (float)qh[c][0] * (float)kh[c][0] + (float)qh[c][1] * (float)kh[c][1];
#endif
    l[j] = d * scale;
  }

  float m = l[0];
#pragma unroll
  for (int j = 1; j < 9; ++j) m = fmaxf(m, l[j]);
  float s = 0.f;
#pragma unroll
  for (int j = 0; j < 9; ++j) { l[j] = expf(l[j] - m); s += l[j]; }
  const float rs = 1.f / s;

  // pass 2: out += p[j] * v (v from LDS)
  float out[32];
#pragma unroll
  for (int c = 0; c < 32; ++c) out[c] = 0.f;
#pragma unroll
  for (int j = 0; j < 9; ++j) {
    const char* vp = kv + rtap[j] * 560 + 256 + head * 64;
    half8 vh[4];
    vh[0] = *(const half8*)(vp);
    vh[1] = *(const half8*)(vp + 16);
    vh[2] = *(const half8*)(vp + 32);
    vh[3] = *(const half8*)(vp + 48);
    const float p = l[j];
#pragma unroll
    for (int g = 0; g < 4; ++g)
#pragma unroll
      for (int e = 0; e < 8; ++e) out[g * 8 + e] = fmaf(p, (float)vh[g][e], out[g * 8 + e]);
  }

  _Float16* yp = y + (base + gty * 56 + gtx) * (size_t)CDIM + cb + head * 32;
  half8 oh[4];
#pragma unroll
  for (int g = 0; g < 4; ++g) {
#pragma unroll
    for (int e = 0; e < 8; ++e) oh[g][e] = (_Float16)(out[g * 8 + e] * rs);
    *(half8*)(yp + g * 8) = oh[g];
  }
}

extern "C" void kernel_launch(void* const* d_in, const int* in_sizes, int n_in,
                              void* d_out, int out_size, void* d_ws, size_t ws_size,
                              hipStream_t stream) {
  const float* x = (const float*)d_in[0];       // [16,56,56,384]
  const float* w_qkv = (const float*)d_in[1];   // [1152,384]
  const float* w_proj = (const float*)d_in[2];  // [384,384]
  const float* b_proj = (const float*)d_in[3];  // [384]
  float* out = (float*)d_out;                   // [50176,384]

  _Float16* xh = (_Float16*)d_ws;                     // 50176*384
  _Float16* wqh = xh + (size_t)NTOK * CDIM;           // 1152*384
  _Float16* wph = wqh + (size_t)ROWQKV * CDIM;        // 384*384
  _Float16* qkvh = wph + (size_t)CDIM * CDIM;         // 50176*1152
  _Float16* yh = qkvh + (size_t)NTOK * ROWQKV;        // 50176*384

  conv_all<<<2048, 256, 0, stream>>>(x, w_qkv, w_proj, xh, wqh, wph);

  gemm3<true><<<(NTOK / 128) * (ROWQKV / 128), 256, 0, stream>>>(
      xh, wqh, nullptr, qkvh, ROWQKV, CDIM);

  // LDS-tiled attention: one launch per dilation (constexpr H, exact LDS)
  attn_tile<1><<<dim3(49, 16), 256, 0, stream>>>(qkvh, yh);
  attn_tile<2><<<dim3(49, 16), 256, 0, stream>>>(qkvh, yh);
  attn_tile<3><<<dim3(49, 16), 256, 0, stream>>>(qkvh, yh);

  gemm3<false><<<(NTOK / 128) * (CDIM / 128), 256, 0, stream>>>(
      yh, wph, b_proj, out, CDIM, CDIM);
}

// Round 13
// 178.486 us; speedup vs baseline: 1.2013x; 1.2013x over previous
//
#include <hip/hip_runtime.h>
#include <hip/hip_bf16.h>

// MultiDilatelocalAttention, round 13: round 8 exactly, plus ONE change —
// XCD-chunked block remap on the attention grid (2352 = 8*294), so each XCD
// processes a contiguous token range and the 9 local k/v taps hit its own L2
// (working window ~3MB < 4MB) instead of falling through to the LLC.

#define NTOK 50176
#define ROWQKV 1152
#define CDIM 384

typedef _Float16 half2v __attribute__((ext_vector_type(2)));
typedef _Float16 half8 __attribute__((ext_vector_type(8)));
typedef float floatx4 __attribute__((ext_vector_type(4)));

typedef __attribute__((address_space(1))) const unsigned int GU32;
typedef __attribute__((address_space(3))) unsigned int LU32;

// ---------------- fused fp32 -> fp16 conversion: x, w_qkv, w_proj ----------------
#define N_X4 (NTOK * CDIM / 4)
#define N_Q4 (ROWQKV * CDIM / 4)
#define N_P4 (CDIM * CDIM / 4)

__global__ __launch_bounds__(256) void conv_all(const float* __restrict__ x,
                                                const float* __restrict__ wq,
                                                const float* __restrict__ wp,
                                                _Float16* __restrict__ xh,
                                                _Float16* __restrict__ wqh,
                                                _Float16* __restrict__ wph) {
  const int total = N_X4 + N_Q4 + N_P4;
  int i = blockIdx.x * 256 + threadIdx.x;
  const int stride = gridDim.x * 256;
  for (; i < total; i += stride) {
    const float* src;
    _Float16* dst;
    int k;
    if (i < N_X4) { src = x; dst = xh; k = i; }
    else if (i < N_X4 + N_Q4) { src = wq; dst = wqh; k = i - N_X4; }
    else { src = wp; dst = wph; k = i - N_X4 - N_Q4; }
    float4 v = ((const float4*)src)[k];
    union { _Float16 h[4]; uint2 u; } o;
    o.h[0] = (_Float16)v.x; o.h[1] = (_Float16)v.y;
    o.h[2] = (_Float16)v.z; o.h[3] = (_Float16)v.w;
    ((uint2*)dst)[k] = o.u;
  }
}

// ---------------- f16 MFMA GEMM (round-8 exact): C = A * B^T, dbuf + vmcnt(4) ----------------
template <bool HALF_OUT>
__global__ __launch_bounds__(256) void gemm3(const _Float16* __restrict__ A,
                                             const _Float16* __restrict__ B,
                                             const float* __restrict__ bias,
                                             void* __restrict__ Cout,
                                             int N, int K) {
  __shared__ _Float16 Asl[2][128 * 32];
  __shared__ _Float16 Bsl[2][128 * 32];
  const int tid = threadIdx.x;
  const int lane = tid & 63;
  const int wv = tid >> 6;
  const int wr = wv >> 1, wc = wv & 1;

  const int nN = N >> 7;
  const int p = blockIdx.x;
  const int l = (p & 7) * (gridDim.x >> 3) + (p >> 3);
  const size_t row0 = (size_t)(l / nN) * 128;
  const int col0 = (l % nN) * 128;
  const int NT = K / 32;

  const int srow = tid >> 2;
  const int gslot = (tid & 3) ^ ((srow >> 1) & 3);
  const _Float16* Abase = A + (row0 + srow) * (size_t)K + gslot * 8;
  const _Float16* Bbase = B + ((size_t)(col0 + srow)) * (size_t)K + gslot * 8;
  char* AsB = (char*)Asl;
  char* BsB = (char*)Bsl;

  auto stage = [&](int k0, int buf) {
    __builtin_amdgcn_global_load_lds((GU32*)(Abase + k0),
                                     (LU32*)(AsB + buf * 8192 + tid * 16), 16, 0, 0);
    __builtin_amdgcn_global_load_lds((GU32*)(Abase + (size_t)64 * K + k0),
                                     (LU32*)(AsB + buf * 8192 + tid * 16 + 4096), 16, 0, 0);
    __builtin_amdgcn_global_load_lds((GU32*)(Bbase + k0),
                                     (LU32*)(BsB + buf * 8192 + tid * 16), 16, 0, 0);
    __builtin_amdgcn_global_load_lds((GU32*)(Bbase + (size_t)64 * K + k0),
                                     (LU32*)(BsB + buf * 8192 + tid * 16 + 4096), 16, 0, 0);
  };

  const int fr = lane & 15;
  const int fq = lane >> 4;
  const int rpos = (fq ^ ((fr >> 1) & 3)) * 8;

  floatx4 acc[4][4];
#pragma unroll
  for (int i = 0; i < 4; ++i)
#pragma unroll
    for (int j = 0; j < 4; ++j) acc[i][j] = (floatx4){0.f, 0.f, 0.f, 0.f};

  stage(0, 0);
  asm volatile("s_waitcnt vmcnt(0)" ::: "memory");
  __builtin_amdgcn_s_barrier();

  int cur = 0;
  for (int t = 0; t < NT; ++t) {
    if (t + 1 < NT) {
      stage((t + 1) * 32, cur ^ 1);
      asm volatile("s_waitcnt vmcnt(4)" ::: "memory");
    } else {
      asm volatile("s_waitcnt vmcnt(0)" ::: "memory");
    }
    __builtin_amdgcn_s_barrier();
    __builtin_amdgcn_sched_barrier(0);
    half8 af[4], bf[4];
#pragma unroll
    for (int f = 0; f < 4; ++f) {
      af[f] = *(const half8*)&Asl[cur][(wr * 64 + f * 16 + fr) * 32 + rpos];
      bf[f] = *(const half8*)&Bsl[cur][(wc * 64 + f * 16 + fr) * 32 + rpos];
    }
#pragma unroll
    for (int i = 0; i < 4; ++i)
#pragma unroll
      for (int j = 0; j < 4; ++j)
        acc[i][j] = __builtin_amdgcn_mfma_f32_16x16x32_f16(af[i], bf[j], acc[i][j], 0, 0, 0);
    __builtin_amdgcn_sched_barrier(0);
    __builtin_amdgcn_s_barrier();
    cur ^= 1;
  }

  const int crow = wr * 64 + (lane >> 4) * 4;
  const int ccol = wc * 64 + (lane & 15);
#pragma unroll
  for (int fm = 0; fm < 4; ++fm) {
#pragma unroll
    for (int fn = 0; fn < 4; ++fn) {
      const size_t r0 = (row0 + crow + fm * 16) * (size_t)N + col0 + ccol + fn * 16;
      if (HALF_OUT) {
        _Float16* Cc = (_Float16*)Cout;
#pragma unroll
        for (int j = 0; j < 4; ++j) Cc[r0 + (size_t)j * N] = (_Float16)acc[fm][fn][j];
      } else {
        float* Cc = (float*)Cout;
        const float bz = bias[col0 + ccol + fn * 16];
#pragma unroll
        for (int j = 0; j < 4; ++j) Cc[r0 + (size_t)j * N] = acc[fm][fn][j] + bz;
      }
    }
  }
}

// ---------------- Local attention: one thread per (token, head), XCD-chunked ----------------
// Grid 2352 = 8*294; block p -> logical l = (p&7)*294 + (p>>3), so each XCD
// owns a contiguous ~6272-token range and the 9 k/v taps (±dil rows) hit its
// private L2 instead of the LLC.
__global__ __launch_bounds__(256) void attn_kernel(const _Float16* __restrict__ qkv,
                                                   _Float16* __restrict__ y) {
  const int p = blockIdx.x;
  const int l = (p & 7) * (gridDim.x >> 3) + (p >> 3);
  const int idx = l * 256 + threadIdx.x;  // token*12 + head
  const int head = idx % 12;
  const int token = idx / 12;
  const int branch = head >> 2;
  const int dil = branch + 1;
  const int cbase = branch * 128 + (head & 3) * 32;
  const int xx = token % 56;
  const int yy = (token / 56) % 56;
  const int bimg = token / 3136;
  const float scale = 0.17677669529663687f;  // 1/sqrt(32)

  const _Float16* qp = qkv + (size_t)token * ROWQKV + cbase;
  half2v qh[16];
  *(half8*)&qh[0] = *(const half8*)(qp);
  *(half8*)&qh[4] = *(const half8*)(qp + 8);
  *(half8*)&qh[8] = *(const half8*)(qp + 16);
  *(half8*)&qh[12] = *(const half8*)(qp + 24);

  const size_t nbase = (size_t)bimg * 3136;

  float lg[9];
#pragma unroll
  for (int j = 0; j < 9; ++j) {
    const int ny = yy + (j / 3 - 1) * dil;
    const int nx = xx + (j % 3 - 1) * dil;
    float d = 0.f;
    if ((unsigned)ny < 56u && (unsigned)nx < 56u) {
      const _Float16* kp = qkv + (nbase + ny * 56 + nx) * ROWQKV + 384 + cbase;
      half2v kh[16];
      *(half8*)&kh[0] = *(const half8*)(kp);
      *(half8*)&kh[4] = *(const half8*)(kp + 8);
      *(half8*)&kh[8] = *(const half8*)(kp + 16);
      *(half8*)&kh[12] = *(const half8*)(kp + 24);
#if __has_builtin(__builtin_amdgcn_fdot2)
#pragma unroll
      for (int c = 0; c < 16; ++c) d = __builtin_amdgcn_fdot2(qh[c], kh[c], d, false);
#else
#pragma unroll
      for (int c = 0; c < 16; ++c)
        d += (float)qh[c][0] * (float)kh[c][0] + (float)qh[c][1] * (float)kh[c][1];
#endif
    }
    lg[j] = d * scale;
  }

  float m = lg[0];
#pragma unroll
  for (int j = 1; j < 9; ++j) m = fmaxf(m, lg[j]);
  float s = 0.f;
#pragma unroll
  for (int j = 0; j < 9; ++j) { lg[j] = expf(lg[j] - m); s += lg[j]; }
  const float rs = 1.f / s;

  float out[32];
#pragma unroll
  for (int c = 0; c < 32; ++c) out[c] = 0.f;
#pragma unroll
  for (int j = 0; j < 9; ++j) {
    const int ny = yy + (j / 3 - 1) * dil;
    const int nx = xx + (j % 3 - 1) * dil;
    if ((unsigned)ny < 56u && (unsigned)nx < 56u) {
      const _Float16* vp = qkv + (nbase + ny * 56 + nx) * ROWQKV + 768 + cbase;
      half8 vh[4];
      vh[0] = *(const half8*)(vp);
      vh[1] = *(const half8*)(vp + 8);
      vh[2] = *(const half8*)(vp + 16);
      vh[3] = *(const half8*)(vp + 24);
      const float pw = lg[j];
#pragma unroll
      for (int g = 0; g < 4; ++g)
#pragma unroll
        for (int e = 0; e < 8; ++e) out[g * 8 + e] = fmaf(pw, (float)vh[g][e], out[g * 8 + e]);
    }
  }

  _Float16* yp = y + (size_t)token * CDIM + cbase;
  half8 oh[4];
#pragma unroll
  for (int g = 0; g < 4; ++g) {
#pragma unroll
    for (int e = 0; e < 8; ++e) oh[g][e] = (_Float16)(out[g * 8 + e] * rs);
    *(half8*)(yp + g * 8) = oh[g];
  }
}

extern "C" void kernel_launch(void* const* d_in, const int* in_sizes, int n_in,
                              void* d_out, int out_size, void* d_ws, size_t ws_size,
                              hipStream_t stream) {
  const float* x = (const float*)d_in[0];       // [16,56,56,384]
  const float* w_qkv = (const float*)d_in[1];   // [1152,384]
  const float* w_proj = (const float*)d_in[2];  // [384,384]
  const float* b_proj = (const float*)d_in[3];  // [384]
  float* out = (float*)d_out;                   // [50176,384]

  _Float16* xh = (_Float16*)d_ws;                     // 50176*384
  _Float16* wqh = xh + (size_t)NTOK * CDIM;           // 1152*384
  _Float16* wph = wqh + (size_t)ROWQKV * CDIM;        // 384*384
  _Float16* qkvh = wph + (size_t)CDIM * CDIM;         // 50176*1152
  _Float16* yh = qkvh + (size_t)NTOK * ROWQKV;        // 50176*384

  conv_all<<<2048, 256, 0, stream>>>(x, w_qkv, w_proj, xh, wqh, wph);

  gemm3<true><<<(NTOK / 128) * (ROWQKV / 128), 256, 0, stream>>>(
      xh, wqh, nullptr, qkvh, ROWQKV, CDIM);

  attn_kernel<<<(NTOK * 12) / 256, 256, 0, stream>>>(qkvh, yh);

  gemm3<false><<<(NTOK / 128) * (CDIM / 128), 256, 0, stream>>>(
      yh, wph, b_proj, out, CDIM, CDIM);
}